// Round 7
// baseline (399.197 us; speedup 1.0000x reference)
//
#include <hip/hip_runtime.h>
#include <math.h>

#define NSRC 32768
#define NTOT 65536
#define NDST 32768
#define DH   256

typedef __attribute__((ext_vector_type(8))) short bf16x8;
typedef __attribute__((ext_vector_type(4))) float f32x4;

__device__ __forceinline__ float wave_reduce(float v) {
#pragma unroll
  for (int off = 32; off > 0; off >>= 1) v += __shfl_xor(v, off, 64);
  return v;
}
__device__ __forceinline__ unsigned short f2bf(float f) {
  union { float f; unsigned u; } v; v.f = f;
  unsigned r = v.u + 0x7FFFu + ((v.u >> 16) & 1u);
  return (unsigned short)(r >> 16);
}
__device__ __forceinline__ float bf2f(unsigned short h) {
  union { unsigned u; float f; } v; v.u = ((unsigned)h) << 16;
  return v.f;
}
__device__ __forceinline__ float4 bf4(ushort4 v) {
  return make_float4(bf2f(v.x), bf2f(v.y), bf2f(v.z), bf2f(v.w));
}
__device__ __forceinline__ void add4(float4& a, const float4 v) {
  a.x += v.x; a.y += v.y; a.z += v.z; a.w += v.w;
}
__device__ __forceinline__ float dot4(const float4 a, const float4 b) {
  return a.x * b.x + a.y * b.y + a.z * b.z + a.w * b.w;
}
__device__ __forceinline__ float4 hsrc4(const float4 v, const float4 bv,
                                        float alpha, float isc) {
  float4 h;
  h.x = v.x + bv.x; h.x = (h.x >= 0.f ? h.x : alpha * h.x) * isc;
  h.y = v.y + bv.y; h.y = (h.y >= 0.f ? h.y : alpha * h.y) * isc;
  h.z = v.z + bv.z; h.z = (h.z >= 0.f ? h.z : alpha * h.z) * isc;
  h.w = v.w + bv.w; h.w = (h.w >= 0.f ? h.w : alpha * h.w) * isc;
  return h;
}

// ---------------- W -> Wt (transpose + bf16) --------------------------------
__global__ __launch_bounds__(256) void k_cvtW(const float* __restrict__ W,
                                              unsigned short* __restrict__ Wt) {
  const int n = blockIdx.x, k = threadIdx.x;
  Wt[n * 256 + k] = f2bf(W[(size_t)k * 256 + n]);
}

// ---------------- MFMA GEMM: Wt half staged in LDS, fragment-linear ---------
// Block: 256 thr (4 waves), 128 rows x 128 N-cols. Grid 1024.
// rowgrp=(bid&7)|((bid>>4)<<3), nhalf=(bid>>3)&1 -> nhalf twins 8 apart
// (same XCD -> feat strip L2 reuse; verified by FETCH_SIZE ~33 MB).
// LDS layout: slot (f=nt*8+ks, lane) holds the exact 16B A-fragment
// lane needs -> main-loop ds_read is base+lane*16 (conflict-free).
__global__ __launch_bounds__(256) void k_gemm_mfma(
    const float* __restrict__ A, const unsigned short* __restrict__ Wt,
    unsigned short* __restrict__ mb) {
  __shared__ unsigned short wl[32768];  // 64 KB
  const int bid = blockIdx.x;
  const int rowgrp = (bid & 7) | ((bid >> 4) << 3);
  const int nhalf = (bid >> 3) & 1;
  const int t = threadIdx.x;
  const int lane = t & 63;
  const int wv = t >> 6;
  const int ln = lane & 15;
  const int kq = lane >> 4;          // 0..3
  const int row0 = rowgrp * 128 + wv * 32 + ln;  // strip 0; strip 1 = +16

  // ---- feat strips -> bf16 fragments (issued before staging: latency hides)
  bf16x8 bs[2][8];
#pragma unroll
  for (int s = 0; s < 2; ++s) {
    const float* ap = A + (size_t)(row0 + s * 16) * 256 + kq * 8;
#pragma unroll
    for (int ks = 0; ks < 8; ++ks) {
      float4 a0 = *(const float4*)(ap + ks * 32);
      float4 a1 = *(const float4*)(ap + ks * 32 + 4);
      bf16x8 v;
      v[0] = (short)f2bf(a0.x); v[1] = (short)f2bf(a0.y);
      v[2] = (short)f2bf(a0.z); v[3] = (short)f2bf(a0.w);
      v[4] = (short)f2bf(a1.x); v[5] = (short)f2bf(a1.y);
      v[6] = (short)f2bf(a1.z); v[7] = (short)f2bf(a1.w);
      bs[s][ks] = v;
    }
  }

  // ---- stage Wt half into LDS in fragment order (4096 slots x 16 B)
#pragma unroll
  for (int r = 0; r < 16; ++r) {
    const int flat = r * 256 + t;
    const int f = flat >> 6;          // nt*8 + ks
    const int ls = flat & 63;
    const int n = nhalf * 128 + (f >> 3) * 16 + (ls & 15);
    const int k = ((ls >> 4) << 3) + (f & 7) * 32;
    *(bf16x8*)(wl + flat * 8) = *(const bf16x8*)(Wt + (size_t)n * 256 + k);
  }
  __syncthreads();

  f32x4 acc[2][8];
#pragma unroll
  for (int s = 0; s < 2; ++s)
#pragma unroll
    for (int i = 0; i < 8; ++i) acc[s][i] = (f32x4){0.f, 0.f, 0.f, 0.f};

#pragma unroll
  for (int nt = 0; nt < 8; ++nt) {
#pragma unroll
    for (int ks = 0; ks < 8; ++ks) {
      bf16x8 af = *(const bf16x8*)(wl + ((nt * 8 + ks) * 64 + lane) * 8);
      acc[0][nt] = __builtin_amdgcn_mfma_f32_16x16x32_bf16(af, bs[0][ks], acc[0][nt], 0, 0, 0);
      acc[1][nt] = __builtin_amdgcn_mfma_f32_16x16x32_bf16(af, bs[1][ks], acc[1][nt], 0, 0, 0);
    }
  }

  const int n0 = nhalf * 128 + kq * 4;
#pragma unroll
  for (int s = 0; s < 2; ++s)
#pragma unroll
    for (int nt = 0; nt < 8; ++nt) {
      ushort4 o;
      o.x = f2bf(acc[s][nt][0]); o.y = f2bf(acc[s][nt][1]);
      o.z = f2bf(acc[s][nt][2]); o.w = f2bf(acc[s][nt][3]);
      *(ushort4*)(mb + (size_t)(row0 + s * 16) * 256 + n0 + nt * 16) = o;
    }
}

// ---------------- per-src-row inverse norm of prelu(m+b) --------------------
__global__ __launch_bounds__(256) void k_inn(const unsigned short* __restrict__ mb,
                                             const float* __restrict__ b,
                                             const float* __restrict__ pa,
                                             float* __restrict__ inn) {
  const int row = blockIdx.x * 4 + (threadIdx.x >> 6);
  const int lane = threadIdx.x & 63;
  const int c = lane * 4;
  float4 v = bf4(*(const ushort4*)(mb + (size_t)row * 256 + c));
  float4 bv = *(const float4*)(b + c);
  const float alpha = pa[0];
  float4 h = hsrc4(v, bv, alpha, 1.0f);
  float ss = wave_reduce(dot4(h, h));
  if (lane == 0) inn[row] = 1.0f / fmaxf(sqrtf(ss), 1e-8f);
}

// ---------------- CSR build (pos graph only) --------------------------------
__global__ __launch_bounds__(256) void k_deg(const int* __restrict__ dst,
                                             int* __restrict__ deg, int nE) {
  const int e = blockIdx.x * 256 + threadIdx.x;
  if (e < nE) atomicAdd(&deg[dst[e] - NSRC], 1);
}

__global__ __launch_bounds__(256) void k_scan(const int* __restrict__ deg,
                                              int* __restrict__ rowStart) {
  __shared__ int tot[256];
  const int t = threadIdx.x;
  const int base = t * 128;
  int s = 0;
  for (int i = 0; i < 128; ++i) s += deg[base + i];
  tot[t] = s;
  __syncthreads();
  for (int off = 1; off < 256; off <<= 1) {
    int v = (t >= off) ? tot[t - off] : 0;
    __syncthreads();
    tot[t] += v;
    __syncthreads();
  }
  int pre = (t == 0) ? 0 : tot[t - 1];
  for (int i = 0; i < 128; ++i) {
    rowStart[base + i] = pre;
    pre += deg[base + i];
  }
  if (t == 255) rowStart[NDST] = pre;
}

__global__ __launch_bounds__(256) void k_fill(const int* __restrict__ src,
                                              const int* __restrict__ dst,
                                              const int* __restrict__ rowStart,
                                              int* __restrict__ cur,
                                              int* __restrict__ eSrc, int nE) {
  const int e = blockIdx.x * 256 + threadIdx.x;
  if (e >= nE) return;
  const int d = dst[e] - NSRC;
  const int p = atomicAdd(&cur[d], 1);
  eSrc[rowStart[d] + p] = src[e];
}

// ---------------- parallel claim: one thread per NEG edge, CAS matching -----
__global__ __launch_bounds__(256) void k_claim(const int* __restrict__ nsrc,
                                               const int* __restrict__ ndst,
                                               const int* __restrict__ rsP,
                                               const int* __restrict__ esP,
                                               int* __restrict__ claim, int nEn) {
  const int i = blockIdx.x * 256 + threadIdx.x;
  if (i >= nEn) return;
  const int d = ndst[i] - NSRC;
  const int s = nsrc[i];
  const int p1 = rsP[d + 1];
  for (int j = rsP[d]; j < p1; ++j) {
    if (esP[j] == s) {
      if (atomicCAS(&claim[j], 0, 1) == 0) return;
    }
  }
}

// ---------------- fused: agg(P,N)+prelu+norm+loss terms+LSE accumulation ----
__global__ __launch_bounds__(256) void k_fused(const unsigned short* __restrict__ mb,
                                               const float* __restrict__ inn,
                                               const int* __restrict__ rsP,
                                               const int* __restrict__ esP,
                                               const int* __restrict__ claim,
                                               const int* __restrict__ degN,
                                               const float* __restrict__ b,
                                               const float* __restrict__ pa,
                                               float* __restrict__ hraw,
                                               float* __restrict__ red) {
  const int row = blockIdx.x * 4 + (threadIdx.x >> 6);
  const int lane = threadIdx.x & 63;
  const int w = threadIdx.x >> 6;
  const int c = lane * 4;
  const int p0 = rsP[row], p1 = rsP[row + 1];
  const int cN = degN[row];
  const float4 bv = *(const float4*)(b + c);
  const float alpha = pa[0];

  float4 self = bf4(*(const ushort4*)(mb + (size_t)(NSRC + row) * 256 + c));
  float4 aP0 = self, aP1 = {0.f, 0.f, 0.f, 0.f};
  float4 aN0 = self, aN1 = {0.f, 0.f, 0.f, 0.f};
  float4 sP0 = {0.f, 0.f, 0.f, 0.f}, sP1 = {0.f, 0.f, 0.f, 0.f};
  float4 sN0 = {0.f, 0.f, 0.f, 0.f}, sN1 = {0.f, 0.f, 0.f, 0.f};

  int e = p0;
  for (; e + 1 < p1; e += 2) {
    const int s0 = esP[e], s1 = esP[e + 1];
    const int cl0 = claim[e], cl1 = claim[e + 1];
    const float i0 = inn[s0], i1 = inn[s1];
    float4 v0 = bf4(*(const ushort4*)(mb + (size_t)s0 * 256 + c));
    float4 v1 = bf4(*(const ushort4*)(mb + (size_t)s1 * 256 + c));
    float4 h0 = hsrc4(v0, bv, alpha, i0);
    float4 h1 = hsrc4(v1, bv, alpha, i1);
    add4(aP0, v0); add4(sP0, h0);
    add4(aP1, v1); add4(sP1, h1);
    if (cl0) { add4(aN0, v0); add4(sN0, h0); }
    if (cl1) { add4(aN1, v1); add4(sN1, h1); }
  }
  if (e < p1) {
    const int s0 = esP[e];
    const int cl0 = claim[e];
    const float i0 = inn[s0];
    float4 v0 = bf4(*(const ushort4*)(mb + (size_t)s0 * 256 + c));
    float4 h0 = hsrc4(v0, bv, alpha, i0);
    add4(aP0, v0); add4(sP0, h0);
    if (cl0) { add4(aN0, v0); add4(sN0, h0); }
  }
  add4(aP0, aP1); add4(aN0, aN1); add4(sP0, sP1); add4(sN0, sN1);

  const float invP = 1.0f / (float)(p1 - p0 + 1);
  const float invN = 1.0f / (float)(cN + 1);
  float4 hp, hn;
  hp.x = aP0.x * invP + bv.x; hp.x = hp.x >= 0.f ? hp.x : alpha * hp.x;
  hp.y = aP0.y * invP + bv.y; hp.y = hp.y >= 0.f ? hp.y : alpha * hp.y;
  hp.z = aP0.z * invP + bv.z; hp.z = hp.z >= 0.f ? hp.z : alpha * hp.z;
  hp.w = aP0.w * invP + bv.w; hp.w = hp.w >= 0.f ? hp.w : alpha * hp.w;
  hn.x = aN0.x * invN + bv.x; hn.x = hn.x >= 0.f ? hn.x : alpha * hn.x;
  hn.y = aN0.y * invN + bv.y; hn.y = hn.y >= 0.f ? hn.y : alpha * hn.y;
  hn.z = aN0.z * invN + bv.z; hn.z = hn.z >= 0.f ? hn.z : alpha * hn.z;
  hn.w = aN0.w * invN + bv.w; hn.w = hn.w >= 0.f ? hn.w : alpha * hn.w;

  *(float4*)(hraw + (size_t)row * 256 + c) = hp;  // h_pos[NSRC:] output

  float ssP = wave_reduce(dot4(hp, hp));
  float ssN = wave_reduce(dot4(hn, hn));
  const float iP = 1.0f / fmaxf(sqrtf(ssP), 1e-8f);
  const float iN = 1.0f / fmaxf(sqrtf(ssN), 1e-8f);
  float4 xp = hp, xn = hn;
  xp.x *= iP; xp.y *= iP; xp.z *= iP; xp.w *= iP;
  xn.x *= iN; xn.y *= iN; xn.z *= iN; xn.w *= iN;

  float pos = wave_reduce(dot4(xp, xn));
  float n1 = wave_reduce(dot4(xp, sN0));
  float n2 = wave_reduce(dot4(xn, sP0));

  // fused LSE accumulation: exp(pos)+exp(pos+n1)+exp(pos+n2), and pos
  __shared__ float se[4], sp[4];
  if (lane == 0) {
    se[w] = expf(pos) + expf(pos + n1) + expf(pos + n2);
    sp[w] = pos;
  }
  __syncthreads();
  if (threadIdx.x == 0) {
    atomicAdd(red + 0, se[0] + se[1] + se[2] + se[3]);
    atomicAdd(red + 1, sp[0] + sp[1] + sp[2] + sp[3]);
  }
}

__global__ void k_final(const float* __restrict__ red, float* __restrict__ out) {
  out[0] = logf(red[0]) - red[1];
}

extern "C" void kernel_launch(void* const* d_in, const int* in_sizes, int n_in,
                              void* d_out, int out_size, void* d_ws, size_t ws_size,
                              hipStream_t stream) {
  const float* feat = (const float*)d_in[0];
  const int*   src  = (const int*)d_in[1];
  const int*   dst  = (const int*)d_in[2];
  const int*   nsrc = (const int*)d_in[3];
  const int*   ndst = (const int*)d_in[4];
  const float* W    = (const float*)d_in[5];
  const float* b    = (const float*)d_in[6];
  const float* pa   = (const float*)d_in[7];
  const int nE  = in_sizes[1];
  const int nEn = in_sizes[3];
  float* out = (float*)d_out;

  unsigned short* mb = (unsigned short*)d_ws;            // NTOT*256 bf16
  unsigned short* Wt = mb + (size_t)NTOT * 256;          // 256*256 bf16
  float* inn  = (float*)(Wt + 256 * 256);                // NSRC
  float* red  = inn + NSRC;                              // 8
  int* degP  = (int*)(red + 8);                          // NDST
  int* curP  = degP + NDST;                              // NDST
  int* degN  = curP + NDST;                              // NDST
  int* rsP   = degN + NDST;                              // NDST+1
  int* eSrcP = rsP + NDST + 1;                           // nE
  int* claim = eSrcP + nE;                               // nE ints

  hipMemsetAsync(degP, 0, 3 * (size_t)NDST * sizeof(int), stream);
  hipMemsetAsync(claim, 0, (size_t)nE * sizeof(int), stream);
  hipMemsetAsync(red, 0, 8 * sizeof(float), stream);

  k_cvtW<<<256, 256, 0, stream>>>(W, Wt);
  k_gemm_mfma<<<1024, 256, 0, stream>>>(feat, Wt, mb);
  k_inn<<<NSRC / 4, 256, 0, stream>>>(mb, b, pa, inn);

  k_deg<<<(nE + 255) / 256, 256, 0, stream>>>(dst, degP, nE);
  k_deg<<<(nEn + 255) / 256, 256, 0, stream>>>(ndst, degN, nEn);
  k_scan<<<1, 256, 0, stream>>>(degP, rsP);
  k_fill<<<(nE + 255) / 256, 256, 0, stream>>>(src, dst, rsP, curP, eSrcP, nE);
  k_claim<<<(nEn + 255) / 256, 256, 0, stream>>>(nsrc, ndst, rsP, eSrcP, claim, nEn);

  k_fused<<<NDST / 4, 256, 0, stream>>>(mb, inn, rsP, eSrcP, claim, degN, b, pa,
                                        out + 1, red);

  k_final<<<1, 1, 0, stream>>>(red, out);
}

// Round 8
// 249.188 us; speedup vs baseline: 1.6020x; 1.6020x over previous
//
#include <hip/hip_runtime.h>
#include <math.h>

#define NSRC 32768
#define NTOT 65536
#define NDST 32768
#define DH   256

typedef __attribute__((ext_vector_type(8))) short bf16x8;
typedef __attribute__((ext_vector_type(4))) float f32x4;

__device__ __forceinline__ float wave_reduce(float v) {
#pragma unroll
  for (int off = 32; off > 0; off >>= 1) v += __shfl_xor(v, off, 64);
  return v;
}
__device__ __forceinline__ unsigned short f2bf(float f) {
  union { float f; unsigned u; } v; v.f = f;
  unsigned r = v.u + 0x7FFFu + ((v.u >> 16) & 1u);
  return (unsigned short)(r >> 16);
}
__device__ __forceinline__ float bf2f(unsigned short h) {
  union { unsigned u; float f; } v; v.u = ((unsigned)h) << 16;
  return v.f;
}
__device__ __forceinline__ float4 bf4(ushort4 v) {
  return make_float4(bf2f(v.x), bf2f(v.y), bf2f(v.z), bf2f(v.w));
}
__device__ __forceinline__ void add4(float4& a, const float4 v) {
  a.x += v.x; a.y += v.y; a.z += v.z; a.w += v.w;
}
__device__ __forceinline__ float dot4(const float4 a, const float4 b) {
  return a.x * b.x + a.y * b.y + a.z * b.z + a.w * b.w;
}
__device__ __forceinline__ float4 hsrc4(const float4 v, const float4 bv,
                                        float alpha, float isc) {
  float4 h;
  h.x = v.x + bv.x; h.x = (h.x >= 0.f ? h.x : alpha * h.x) * isc;
  h.y = v.y + bv.y; h.y = (h.y >= 0.f ? h.y : alpha * h.y) * isc;
  h.z = v.z + bv.z; h.z = (h.z >= 0.f ? h.z : alpha * h.z) * isc;
  h.w = v.w + bv.w; h.w = (h.w >= 0.f ? h.w : alpha * h.w) * isc;
  return h;
}

// ---------------- W -> Wt (transpose + bf16) --------------------------------
__global__ __launch_bounds__(256) void k_cvtW(const float* __restrict__ W,
                                              unsigned short* __restrict__ Wt) {
  const int n = blockIdx.x, k = threadIdx.x;
  Wt[n * 256 + k] = f2bf(W[(size_t)k * 256 + n]);
}

// ---------------- MFMA GEMM: Wt half staged in LDS, fragment-linear ---------
__global__ __launch_bounds__(256) void k_gemm_mfma(
    const float* __restrict__ A, const unsigned short* __restrict__ Wt,
    unsigned short* __restrict__ mb) {
  __shared__ unsigned short wl[32768];  // 64 KB
  const int bid = blockIdx.x;
  const int rowgrp = (bid & 7) | ((bid >> 4) << 3);
  const int nhalf = (bid >> 3) & 1;
  const int t = threadIdx.x;
  const int lane = t & 63;
  const int wv = t >> 6;
  const int ln = lane & 15;
  const int kq = lane >> 4;          // 0..3
  const int row0 = rowgrp * 128 + wv * 32 + ln;  // strip 0; strip 1 = +16

  bf16x8 bs[2][8];
#pragma unroll
  for (int s = 0; s < 2; ++s) {
    const float* ap = A + (size_t)(row0 + s * 16) * 256 + kq * 8;
#pragma unroll
    for (int ks = 0; ks < 8; ++ks) {
      float4 a0 = *(const float4*)(ap + ks * 32);
      float4 a1 = *(const float4*)(ap + ks * 32 + 4);
      bf16x8 v;
      v[0] = (short)f2bf(a0.x); v[1] = (short)f2bf(a0.y);
      v[2] = (short)f2bf(a0.z); v[3] = (short)f2bf(a0.w);
      v[4] = (short)f2bf(a1.x); v[5] = (short)f2bf(a1.y);
      v[6] = (short)f2bf(a1.z); v[7] = (short)f2bf(a1.w);
      bs[s][ks] = v;
    }
  }

#pragma unroll
  for (int r = 0; r < 16; ++r) {
    const int flat = r * 256 + t;
    const int f = flat >> 6;          // nt*8 + ks
    const int ls = flat & 63;
    const int n = nhalf * 128 + (f >> 3) * 16 + (ls & 15);
    const int k = ((ls >> 4) << 3) + (f & 7) * 32;
    *(bf16x8*)(wl + flat * 8) = *(const bf16x8*)(Wt + (size_t)n * 256 + k);
  }
  __syncthreads();

  f32x4 acc[2][8];
#pragma unroll
  for (int s = 0; s < 2; ++s)
#pragma unroll
    for (int i = 0; i < 8; ++i) acc[s][i] = (f32x4){0.f, 0.f, 0.f, 0.f};

#pragma unroll
  for (int nt = 0; nt < 8; ++nt) {
#pragma unroll
    for (int ks = 0; ks < 8; ++ks) {
      bf16x8 af = *(const bf16x8*)(wl + ((nt * 8 + ks) * 64 + lane) * 8);
      acc[0][nt] = __builtin_amdgcn_mfma_f32_16x16x32_bf16(af, bs[0][ks], acc[0][nt], 0, 0, 0);
      acc[1][nt] = __builtin_amdgcn_mfma_f32_16x16x32_bf16(af, bs[1][ks], acc[1][nt], 0, 0, 0);
    }
  }

  const int n0 = nhalf * 128 + kq * 4;
#pragma unroll
  for (int s = 0; s < 2; ++s)
#pragma unroll
    for (int nt = 0; nt < 8; ++nt) {
      ushort4 o;
      o.x = f2bf(acc[s][nt][0]); o.y = f2bf(acc[s][nt][1]);
      o.z = f2bf(acc[s][nt][2]); o.w = f2bf(acc[s][nt][3]);
      *(ushort4*)(mb + (size_t)(row0 + s * 16) * 256 + n0 + nt * 16) = o;
    }
}

// ---------------- per-src-row inverse norm of prelu(m+b) --------------------
__global__ __launch_bounds__(256) void k_inn(const unsigned short* __restrict__ mb,
                                             const float* __restrict__ b,
                                             const float* __restrict__ pa,
                                             float* __restrict__ inn) {
  const int row = blockIdx.x * 4 + (threadIdx.x >> 6);
  const int lane = threadIdx.x & 63;
  const int c = lane * 4;
  float4 v = bf4(*(const ushort4*)(mb + (size_t)row * 256 + c));
  float4 bv = *(const float4*)(b + c);
  const float alpha = pa[0];
  float4 h = hsrc4(v, bv, alpha, 1.0f);
  float ss = wave_reduce(dot4(h, h));
  if (lane == 0) inn[row] = 1.0f / fmaxf(sqrtf(ss), 1e-8f);
}

// ---------------- CSR build (pos graph only) --------------------------------
__global__ __launch_bounds__(256) void k_deg(const int* __restrict__ dst,
                                             int* __restrict__ deg, int nE) {
  const int e = blockIdx.x * 256 + threadIdx.x;
  if (e < nE) atomicAdd(&deg[dst[e] - NSRC], 1);
}

__global__ __launch_bounds__(256) void k_scan(const int* __restrict__ deg,
                                              int* __restrict__ rowStart) {
  __shared__ int tot[256];
  const int t = threadIdx.x;
  const int base = t * 128;
  int s = 0;
  for (int i = 0; i < 128; ++i) s += deg[base + i];
  tot[t] = s;
  __syncthreads();
  for (int off = 1; off < 256; off <<= 1) {
    int v = (t >= off) ? tot[t - off] : 0;
    __syncthreads();
    tot[t] += v;
    __syncthreads();
  }
  int pre = (t == 0) ? 0 : tot[t - 1];
  for (int i = 0; i < 128; ++i) {
    rowStart[base + i] = pre;
    pre += deg[base + i];
  }
  if (t == 255) rowStart[NDST] = pre;
}

__global__ __launch_bounds__(256) void k_fill(const int* __restrict__ src,
                                              const int* __restrict__ dst,
                                              const int* __restrict__ rowStart,
                                              int* __restrict__ cur,
                                              int* __restrict__ eSrc, int nE) {
  const int e = blockIdx.x * 256 + threadIdx.x;
  if (e >= nE) return;
  const int d = dst[e] - NSRC;
  const int p = atomicAdd(&cur[d], 1);
  eSrc[rowStart[d] + p] = src[e];
}

// ---------------- parallel claim: one thread per NEG edge, CAS matching -----
__global__ __launch_bounds__(256) void k_claim(const int* __restrict__ nsrc,
                                               const int* __restrict__ ndst,
                                               const int* __restrict__ rsP,
                                               const int* __restrict__ esP,
                                               int* __restrict__ claim, int nEn) {
  const int i = blockIdx.x * 256 + threadIdx.x;
  if (i >= nEn) return;
  const int d = ndst[i] - NSRC;
  const int s = nsrc[i];
  const int p1 = rsP[d + 1];
  for (int j = rsP[d]; j < p1; ++j) {
    if (esP[j] == s) {
      if (atomicCAS(&claim[j], 0, 1) == 0) return;
    }
  }
}

// ---------------- fused: agg(P,N) + prelu + norm + all loss terms -----------
// NOTE: no __syncthreads, no global atomics here (round-7 regression lesson:
// 16k same-address atomicAdds + block-wide sync after variable loops = +140us)
__global__ __launch_bounds__(256) void k_fused(const unsigned short* __restrict__ mb,
                                               const float* __restrict__ inn,
                                               const int* __restrict__ rsP,
                                               const int* __restrict__ esP,
                                               const int* __restrict__ claim,
                                               const int* __restrict__ degN,
                                               const float* __restrict__ b,
                                               const float* __restrict__ pa,
                                               float* __restrict__ hraw,
                                               float* __restrict__ sims) {
  const int row = blockIdx.x * 4 + (threadIdx.x >> 6);
  const int lane = threadIdx.x & 63;
  const int c = lane * 4;
  const int p0 = rsP[row], p1 = rsP[row + 1];
  const int cN = degN[row];
  const float4 bv = *(const float4*)(b + c);
  const float alpha = pa[0];

  float4 self = bf4(*(const ushort4*)(mb + (size_t)(NSRC + row) * 256 + c));
  float4 aP0 = self, aP1 = {0.f, 0.f, 0.f, 0.f};
  float4 aN0 = self, aN1 = {0.f, 0.f, 0.f, 0.f};
  float4 sP0 = {0.f, 0.f, 0.f, 0.f}, sP1 = {0.f, 0.f, 0.f, 0.f};
  float4 sN0 = {0.f, 0.f, 0.f, 0.f}, sN1 = {0.f, 0.f, 0.f, 0.f};

  int e = p0;
  // 4-wide unroll: 4 independent row-gathers in flight per iteration
  for (; e + 3 < p1; e += 4) {
    const int s0 = esP[e], s1 = esP[e + 1], s2 = esP[e + 2], s3 = esP[e + 3];
    ushort4 r0 = *(const ushort4*)(mb + (size_t)s0 * 256 + c);
    ushort4 r1 = *(const ushort4*)(mb + (size_t)s1 * 256 + c);
    ushort4 r2 = *(const ushort4*)(mb + (size_t)s2 * 256 + c);
    ushort4 r3 = *(const ushort4*)(mb + (size_t)s3 * 256 + c);
    const int cl0 = claim[e], cl1 = claim[e + 1], cl2 = claim[e + 2], cl3 = claim[e + 3];
    const float i0 = inn[s0], i1 = inn[s1], i2 = inn[s2], i3 = inn[s3];
    float4 v0 = bf4(r0), v1 = bf4(r1), v2 = bf4(r2), v3 = bf4(r3);
    float4 h0 = hsrc4(v0, bv, alpha, i0);
    float4 h1 = hsrc4(v1, bv, alpha, i1);
    float4 h2 = hsrc4(v2, bv, alpha, i2);
    float4 h3 = hsrc4(v3, bv, alpha, i3);
    add4(aP0, v0); add4(aP1, v1); add4(aP0, v2); add4(aP1, v3);
    add4(sP0, h0); add4(sP1, h1); add4(sP0, h2); add4(sP1, h3);
    if (cl0) { add4(aN0, v0); add4(sN0, h0); }
    if (cl1) { add4(aN1, v1); add4(sN1, h1); }
    if (cl2) { add4(aN0, v2); add4(sN0, h2); }
    if (cl3) { add4(aN1, v3); add4(sN1, h3); }
  }
  for (; e < p1; ++e) {
    const int s0 = esP[e];
    const int cl0 = claim[e];
    const float i0 = inn[s0];
    float4 v0 = bf4(*(const ushort4*)(mb + (size_t)s0 * 256 + c));
    float4 h0 = hsrc4(v0, bv, alpha, i0);
    add4(aP0, v0); add4(sP0, h0);
    if (cl0) { add4(aN0, v0); add4(sN0, h0); }
  }
  add4(aP0, aP1); add4(aN0, aN1); add4(sP0, sP1); add4(sN0, sN1);

  const float invP = 1.0f / (float)(p1 - p0 + 1);
  const float invN = 1.0f / (float)(cN + 1);
  float4 hp, hn;
  hp.x = aP0.x * invP + bv.x; hp.x = hp.x >= 0.f ? hp.x : alpha * hp.x;
  hp.y = aP0.y * invP + bv.y; hp.y = hp.y >= 0.f ? hp.y : alpha * hp.y;
  hp.z = aP0.z * invP + bv.z; hp.z = hp.z >= 0.f ? hp.z : alpha * hp.z;
  hp.w = aP0.w * invP + bv.w; hp.w = hp.w >= 0.f ? hp.w : alpha * hp.w;
  hn.x = aN0.x * invN + bv.x; hn.x = hn.x >= 0.f ? hn.x : alpha * hn.x;
  hn.y = aN0.y * invN + bv.y; hn.y = hn.y >= 0.f ? hn.y : alpha * hn.y;
  hn.z = aN0.z * invN + bv.z; hn.z = hn.z >= 0.f ? hn.z : alpha * hn.z;
  hn.w = aN0.w * invN + bv.w; hn.w = hn.w >= 0.f ? hn.w : alpha * hn.w;

  *(float4*)(hraw + (size_t)row * 256 + c) = hp;  // h_pos[NSRC:] output

  float ssP = wave_reduce(dot4(hp, hp));
  float ssN = wave_reduce(dot4(hn, hn));
  const float iP = 1.0f / fmaxf(sqrtf(ssP), 1e-8f);
  const float iN = 1.0f / fmaxf(sqrtf(ssN), 1e-8f);
  float4 xp = hp, xn = hn;
  xp.x *= iP; xp.y *= iP; xp.z *= iP; xp.w *= iP;
  xn.x *= iN; xn.y *= iN; xn.z *= iN; xn.w *= iN;

  float pos = wave_reduce(dot4(xp, xn));
  float n1 = wave_reduce(dot4(xp, sN0));
  float n2 = wave_reduce(dot4(xn, sP0));
  if (lane == 0) {
    sims[row] = pos;
    sims[NDST + row] = pos + n1;       // + self-loop term
    sims[2 * NDST + row] = pos + n2;   // + self-loop term
  }
}

// ---------------- final log-sum-exp reduce ----------------------------------
__global__ __launch_bounds__(256) void k_reduce(const float* __restrict__ sims,
                                                float* __restrict__ red) {
  const int i = blockIdx.x * 256 + threadIdx.x;
  const float v = sims[i];
  float e = expf(v);
  float p = (i < NDST) ? v : 0.f;
  e = wave_reduce(e);
  p = wave_reduce(p);
  __shared__ float se[4], sp[4];
  const int lane = threadIdx.x & 63, w = threadIdx.x >> 6;
  if (lane == 0) { se[w] = e; sp[w] = p; }
  __syncthreads();
  if (threadIdx.x == 0) {
    atomicAdd(red + 0, se[0] + se[1] + se[2] + se[3]);
    atomicAdd(red + 1, sp[0] + sp[1] + sp[2] + sp[3]);
  }
}

__global__ void k_final(const float* __restrict__ red, float* __restrict__ out) {
  out[0] = logf(red[0]) - red[1];
}

extern "C" void kernel_launch(void* const* d_in, const int* in_sizes, int n_in,
                              void* d_out, int out_size, void* d_ws, size_t ws_size,
                              hipStream_t stream) {
  const float* feat = (const float*)d_in[0];
  const int*   src  = (const int*)d_in[1];
  const int*   dst  = (const int*)d_in[2];
  const int*   nsrc = (const int*)d_in[3];
  const int*   ndst = (const int*)d_in[4];
  const float* W    = (const float*)d_in[5];
  const float* b    = (const float*)d_in[6];
  const float* pa   = (const float*)d_in[7];
  const int nE  = in_sizes[1];
  const int nEn = in_sizes[3];
  float* out = (float*)d_out;

  unsigned short* mb = (unsigned short*)d_ws;            // NTOT*256 bf16
  unsigned short* Wt = mb + (size_t)NTOT * 256;          // 256*256 bf16
  float* inn  = (float*)(Wt + 256 * 256);                // NSRC
  float* sims = inn + NSRC;                              // 3*NDST
  float* red  = sims + 3 * (size_t)NDST;                 // 8
  int* degP  = (int*)(red + 8);                          // NDST
  int* curP  = degP + NDST;                              // NDST
  int* degN  = curP + NDST;                              // NDST
  int* rsP   = degN + NDST;                              // NDST+1
  int* eSrcP = rsP + NDST + 1;                           // nE
  int* claim = eSrcP + nE;                               // nE ints

  hipMemsetAsync(degP, 0, 3 * (size_t)NDST * sizeof(int), stream);
  hipMemsetAsync(claim, 0, (size_t)nE * sizeof(int), stream);
  hipMemsetAsync(red, 0, 8 * sizeof(float), stream);

  k_cvtW<<<256, 256, 0, stream>>>(W, Wt);
  k_gemm_mfma<<<1024, 256, 0, stream>>>(feat, Wt, mb);
  k_inn<<<NSRC / 4, 256, 0, stream>>>(mb, b, pa, inn);

  k_deg<<<(nE + 255) / 256, 256, 0, stream>>>(dst, degP, nE);
  k_deg<<<(nEn + 255) / 256, 256, 0, stream>>>(ndst, degN, nEn);
  k_scan<<<1, 256, 0, stream>>>(degP, rsP);
  k_fill<<<(nE + 255) / 256, 256, 0, stream>>>(src, dst, rsP, curP, eSrcP, nE);
  k_claim<<<(nEn + 255) / 256, 256, 0, stream>>>(nsrc, ndst, rsP, eSrcP, claim, nEn);

  k_fused<<<NDST / 4, 256, 0, stream>>>(mb, inn, rsP, eSrcP, claim, degN, b, pa,
                                        out + 1, sims);

  k_reduce<<<(3 * NDST) / 256, 256, 0, stream>>>(sims, red);
  k_final<<<1, 1, 0, stream>>>(red, out);
}

// Round 9
// 245.123 us; speedup vs baseline: 1.6286x; 1.0166x over previous
//
#include <hip/hip_runtime.h>
#include <math.h>

#define NSRC 32768
#define NTOT 65536
#define NDST 32768
#define DH   256

typedef __attribute__((ext_vector_type(8))) short bf16x8;
typedef __attribute__((ext_vector_type(4))) float f32x4;

__device__ __forceinline__ float wave_reduce(float v) {
#pragma unroll
  for (int off = 32; off > 0; off >>= 1) v += __shfl_xor(v, off, 64);
  return v;
}
__device__ __forceinline__ unsigned short f2bf(float f) {
  union { float f; unsigned u; } v; v.f = f;
  unsigned r = v.u + 0x7FFFu + ((v.u >> 16) & 1u);
  return (unsigned short)(r >> 16);
}
__device__ __forceinline__ float bf2f(unsigned short h) {
  union { unsigned u; float f; } v; v.u = ((unsigned)h) << 16;
  return v.f;
}
__device__ __forceinline__ float4 bf4(ushort4 v) {
  return make_float4(bf2f(v.x), bf2f(v.y), bf2f(v.z), bf2f(v.w));
}
__device__ __forceinline__ void add4(float4& a, const float4 v) {
  a.x += v.x; a.y += v.y; a.z += v.z; a.w += v.w;
}
__device__ __forceinline__ float4 sub4(const float4 a, const float4 v) {
  return make_float4(a.x - v.x, a.y - v.y, a.z - v.z, a.w - v.w);
}
__device__ __forceinline__ float dot4(const float4 a, const float4 b) {
  return a.x * b.x + a.y * b.y + a.z * b.z + a.w * b.w;
}
__device__ __forceinline__ float4 hsrc4(const float4 v, const float4 bv,
                                        float alpha, float isc) {
  float4 h;
  h.x = v.x + bv.x; h.x = (h.x >= 0.f ? h.x : alpha * h.x) * isc;
  h.y = v.y + bv.y; h.y = (h.y >= 0.f ? h.y : alpha * h.y) * isc;
  h.z = v.z + bv.z; h.z = (h.z >= 0.f ? h.z : alpha * h.z) * isc;
  h.w = v.w + bv.w; h.w = (h.w >= 0.f ? h.w : alpha * h.w) * isc;
  return h;
}

// ---------------- prep: cvtW + degP + degN (merged launches) ----------------
__global__ __launch_bounds__(256) void k_prep(const float* __restrict__ W,
                                              unsigned short* __restrict__ Wt,
                                              const int* __restrict__ dst,
                                              const int* __restrict__ ndst,
                                              int* __restrict__ degP,
                                              int* __restrict__ degN,
                                              int nE, int nEn) {
  int bid = blockIdx.x;
  const int t = threadIdx.x;
  if (bid < 256) {  // W transpose+cast
    Wt[bid * 256 + t] = f2bf(W[(size_t)t * 256 + bid]);
    return;
  }
  bid -= 256;
  const int nbP = (nE + 255) / 256;
  if (bid < nbP) {
    const int e = bid * 256 + t;
    if (e < nE) atomicAdd(&degP[dst[e] - NSRC], 1);
    return;
  }
  bid -= nbP;
  const int e = bid * 256 + t;
  if (e < nEn) atomicAdd(&degN[ndst[e] - NSRC], 1);
}

// ---------------- MFMA GEMM: Wt quarter (32KB) in LDS, 512 thr, grid 1024 ---
// rowgrp=(bid&7)|((bid>>5)<<3), quarter=(bid>>3)&3 -> the 4 quarter-twins of a
// rowgrp are 8 apart in bid -> same XCD -> feat strip L2 reuse.
// LDS slot (f=nt*8+ks, lane) holds lane's exact 16B A-fragment (conflict-free).
__global__ __launch_bounds__(512) void k_gemm_mfma(
    const float* __restrict__ A, const unsigned short* __restrict__ Wt,
    unsigned short* __restrict__ mb) {
  __shared__ unsigned short wl[16384];  // 32 KB
  const int bid = blockIdx.x;
  const int rowgrp = (bid & 7) | ((bid >> 5) << 3);
  const int quarter = (bid >> 3) & 3;
  const int t = threadIdx.x;
  const int lane = t & 63;
  const int wv = t >> 6;             // 0..7
  const int ln = lane & 15;
  const int kq = lane >> 4;          // 0..3
  const int row0 = rowgrp * 256 + wv * 32 + ln;  // strip 0; strip 1 = +16

  // feat strips -> bf16 fragments (issued before staging: latency hides)
  bf16x8 bs[2][8];
#pragma unroll
  for (int s = 0; s < 2; ++s) {
    const float* ap = A + (size_t)(row0 + s * 16) * 256 + kq * 8;
#pragma unroll
    for (int ks = 0; ks < 8; ++ks) {
      float4 a0 = *(const float4*)(ap + ks * 32);
      float4 a1 = *(const float4*)(ap + ks * 32 + 4);
      bf16x8 v;
      v[0] = (short)f2bf(a0.x); v[1] = (short)f2bf(a0.y);
      v[2] = (short)f2bf(a0.z); v[3] = (short)f2bf(a0.w);
      v[4] = (short)f2bf(a1.x); v[5] = (short)f2bf(a1.y);
      v[6] = (short)f2bf(a1.z); v[7] = (short)f2bf(a1.w);
      bs[s][ks] = v;
    }
  }

  // stage Wt quarter into LDS in fragment order (2048 slots x 16 B)
#pragma unroll
  for (int r = 0; r < 4; ++r) {
    const int flat = r * 512 + t;
    const int f = flat >> 6;          // nt*8 + ks, 0..31
    const int ls = flat & 63;
    const int n = quarter * 64 + (f >> 3) * 16 + (ls & 15);
    const int k = ((ls >> 4) << 3) + (f & 7) * 32;
    *(bf16x8*)(wl + flat * 8) = *(const bf16x8*)(Wt + (size_t)n * 256 + k);
  }
  __syncthreads();

  f32x4 acc[2][4];
#pragma unroll
  for (int s = 0; s < 2; ++s)
#pragma unroll
    for (int i = 0; i < 4; ++i) acc[s][i] = (f32x4){0.f, 0.f, 0.f, 0.f};

#pragma unroll
  for (int nt = 0; nt < 4; ++nt) {
#pragma unroll
    for (int ks = 0; ks < 8; ++ks) {
      bf16x8 af = *(const bf16x8*)(wl + ((nt * 8 + ks) * 64 + lane) * 8);
      acc[0][nt] = __builtin_amdgcn_mfma_f32_16x16x32_bf16(af, bs[0][ks], acc[0][nt], 0, 0, 0);
      acc[1][nt] = __builtin_amdgcn_mfma_f32_16x16x32_bf16(af, bs[1][ks], acc[1][nt], 0, 0, 0);
    }
  }

  const int n0 = quarter * 64 + kq * 4;
#pragma unroll
  for (int s = 0; s < 2; ++s)
#pragma unroll
    for (int nt = 0; nt < 4; ++nt) {
      ushort4 o;
      o.x = f2bf(acc[s][nt][0]); o.y = f2bf(acc[s][nt][1]);
      o.z = f2bf(acc[s][nt][2]); o.w = f2bf(acc[s][nt][3]);
      *(ushort4*)(mb + (size_t)(row0 + s * 16) * 256 + n0 + nt * 16) = o;
    }
}

// ---------------- scan (pos degrees -> rowStart) ----------------------------
__global__ __launch_bounds__(256) void k_scan(const int* __restrict__ deg,
                                              int* __restrict__ rowStart) {
  __shared__ int tot[256];
  const int t = threadIdx.x;
  const int base = t * 128;
  int s = 0;
  for (int i = 0; i < 128; ++i) s += deg[base + i];
  tot[t] = s;
  __syncthreads();
  for (int off = 1; off < 256; off <<= 1) {
    int v = (t >= off) ? tot[t - off] : 0;
    __syncthreads();
    tot[t] += v;
    __syncthreads();
  }
  int pre = (t == 0) ? 0 : tot[t - 1];
  for (int i = 0; i < 128; ++i) {
    rowStart[base + i] = pre;
    pre += deg[base + i];
  }
  if (t == 255) rowStart[NDST] = pre;
}

__global__ __launch_bounds__(256) void k_fill(const int* __restrict__ src,
                                              const int* __restrict__ dst,
                                              const int* __restrict__ rowStart,
                                              int* __restrict__ cur,
                                              int* __restrict__ eSrc, int nE) {
  const int e = blockIdx.x * 256 + threadIdx.x;
  if (e >= nE) return;
  const int d = dst[e] - NSRC;
  const int p = atomicAdd(&cur[d], 1);
  eSrc[rowStart[d] + p] = src[e];
}

// ---------------- claim (per NEG edge, CAS) + inn (merged) ------------------
__global__ __launch_bounds__(256) void k_claim_inn(
    const int* __restrict__ nsrc, const int* __restrict__ ndst,
    const int* __restrict__ rsP, const int* __restrict__ esP,
    int* __restrict__ claim, int nEn,
    const unsigned short* __restrict__ mb, const float* __restrict__ b,
    const float* __restrict__ pa, float* __restrict__ inn) {
  int bid = blockIdx.x;
  const int nbC = (nEn + 255) / 256;
  if (bid < nbC) {
    const int i = bid * 256 + threadIdx.x;
    if (i >= nEn) return;
    const int d = ndst[i] - NSRC;
    const int s = nsrc[i];
    const int p1 = rsP[d + 1];
    for (int j = rsP[d]; j < p1; ++j) {
      if (esP[j] == s) {
        if (atomicCAS(&claim[j], 0, 1) == 0) return;
      }
    }
    return;
  }
  bid -= nbC;
  const int row = bid * 4 + (threadIdx.x >> 6);
  const int lane = threadIdx.x & 63;
  const int c = lane * 4;
  float4 v = bf4(*(const ushort4*)(mb + (size_t)row * 256 + c));
  float4 bv = *(const float4*)(b + c);
  const float alpha = pa[0];
  float4 h = hsrc4(v, bv, alpha, 1.0f);
  float ss = wave_reduce(dot4(h, h));
  if (lane == 0) inn[row] = 1.0f / fmaxf(sqrtf(ss), 1e-8f);
}

// ---------------- fused: agg(P,N) + prelu + norm + all loss terms -----------
// Complement trick: accumulate UNclaimed (~20%) into aU/sU; aN=aP-aU, sN=sP-sU.
// No __syncthreads / global atomics here (round-7 regression lesson).
__global__ __launch_bounds__(256) void k_fused(const unsigned short* __restrict__ mb,
                                               const float* __restrict__ inn,
                                               const int* __restrict__ rsP,
                                               const int* __restrict__ esP,
                                               const int* __restrict__ claim,
                                               const int* __restrict__ degN,
                                               const float* __restrict__ b,
                                               const float* __restrict__ pa,
                                               float* __restrict__ hraw,
                                               float* __restrict__ sims) {
  const int row = blockIdx.x * 4 + (threadIdx.x >> 6);
  const int lane = threadIdx.x & 63;
  const int c = lane * 4;
  const int p0 = rsP[row], p1 = rsP[row + 1];
  const int cN = degN[row];
  const float4 bv = *(const float4*)(b + c);
  const float alpha = pa[0];

  float4 self = bf4(*(const ushort4*)(mb + (size_t)(NSRC + row) * 256 + c));
  float4 aP0 = self, aP1 = {0.f, 0.f, 0.f, 0.f};
  float4 sP0 = {0.f, 0.f, 0.f, 0.f}, sP1 = {0.f, 0.f, 0.f, 0.f};
  float4 aU0 = {0.f, 0.f, 0.f, 0.f}, aU1 = {0.f, 0.f, 0.f, 0.f};
  float4 sU0 = {0.f, 0.f, 0.f, 0.f}, sU1 = {0.f, 0.f, 0.f, 0.f};

  int e = p0;
  for (; e + 3 < p1; e += 4) {
    const int s0 = esP[e], s1 = esP[e + 1], s2 = esP[e + 2], s3 = esP[e + 3];
    ushort4 r0 = *(const ushort4*)(mb + (size_t)s0 * 256 + c);
    ushort4 r1 = *(const ushort4*)(mb + (size_t)s1 * 256 + c);
    ushort4 r2 = *(const ushort4*)(mb + (size_t)s2 * 256 + c);
    ushort4 r3 = *(const ushort4*)(mb + (size_t)s3 * 256 + c);
    const int cl0 = claim[e], cl1 = claim[e + 1], cl2 = claim[e + 2], cl3 = claim[e + 3];
    const float i0 = inn[s0], i1 = inn[s1], i2 = inn[s2], i3 = inn[s3];
    float4 v0 = bf4(r0), v1 = bf4(r1), v2 = bf4(r2), v3 = bf4(r3);
    float4 h0 = hsrc4(v0, bv, alpha, i0);
    float4 h1 = hsrc4(v1, bv, alpha, i1);
    float4 h2 = hsrc4(v2, bv, alpha, i2);
    float4 h3 = hsrc4(v3, bv, alpha, i3);
    add4(aP0, v0); add4(aP1, v1); add4(aP0, v2); add4(aP1, v3);
    add4(sP0, h0); add4(sP1, h1); add4(sP0, h2); add4(sP1, h3);
    if (!cl0) { add4(aU0, v0); add4(sU0, h0); }
    if (!cl1) { add4(aU1, v1); add4(sU1, h1); }
    if (!cl2) { add4(aU0, v2); add4(sU0, h2); }
    if (!cl3) { add4(aU1, v3); add4(sU1, h3); }
  }
  for (; e < p1; ++e) {
    const int s0 = esP[e];
    const int cl0 = claim[e];
    const float i0 = inn[s0];
    float4 v0 = bf4(*(const ushort4*)(mb + (size_t)s0 * 256 + c));
    float4 h0 = hsrc4(v0, bv, alpha, i0);
    add4(aP0, v0); add4(sP0, h0);
    if (!cl0) { add4(aU0, v0); add4(sU0, h0); }
  }
  add4(aP0, aP1); add4(sP0, sP1); add4(aU0, aU1); add4(sU0, sU1);
  float4 aN0 = sub4(aP0, aU0);   // self + claimed sum
  float4 sN0 = sub4(sP0, sU0);

  const float invP = 1.0f / (float)(p1 - p0 + 1);
  const float invN = 1.0f / (float)(cN + 1);
  float4 hp, hn;
  hp.x = aP0.x * invP + bv.x; hp.x = hp.x >= 0.f ? hp.x : alpha * hp.x;
  hp.y = aP0.y * invP + bv.y; hp.y = hp.y >= 0.f ? hp.y : alpha * hp.y;
  hp.z = aP0.z * invP + bv.z; hp.z = hp.z >= 0.f ? hp.z : alpha * hp.z;
  hp.w = aP0.w * invP + bv.w; hp.w = hp.w >= 0.f ? hp.w : alpha * hp.w;
  hn.x = aN0.x * invN + bv.x; hn.x = hn.x >= 0.f ? hn.x : alpha * hn.x;
  hn.y = aN0.y * invN + bv.y; hn.y = hn.y >= 0.f ? hn.y : alpha * hn.y;
  hn.z = aN0.z * invN + bv.z; hn.z = hn.z >= 0.f ? hn.z : alpha * hn.z;
  hn.w = aN0.w * invN + bv.w; hn.w = hn.w >= 0.f ? hn.w : alpha * hn.w;

  *(float4*)(hraw + (size_t)row * 256 + c) = hp;  // h_pos[NSRC:] output

  float ssP = wave_reduce(dot4(hp, hp));
  float ssN = wave_reduce(dot4(hn, hn));
  const float iP = 1.0f / fmaxf(sqrtf(ssP), 1e-8f);
  const float iN = 1.0f / fmaxf(sqrtf(ssN), 1e-8f);
  float4 xp = hp, xn = hn;
  xp.x *= iP; xp.y *= iP; xp.z *= iP; xp.w *= iP;
  xn.x *= iN; xn.y *= iN; xn.z *= iN; xn.w *= iN;

  float pos = wave_reduce(dot4(xp, xn));
  float n1 = wave_reduce(dot4(xp, sN0));
  float n2 = wave_reduce(dot4(xn, sP0));
  if (lane == 0) {
    sims[row] = pos;
    sims[NDST + row] = pos + n1;       // + self-loop term
    sims[2 * NDST + row] = pos + n2;   // + self-loop term
  }
}

// ---------------- final log-sum-exp reduce ----------------------------------
__global__ __launch_bounds__(256) void k_reduce(const float* __restrict__ sims,
                                                float* __restrict__ red) {
  const int i = blockIdx.x * 256 + threadIdx.x;
  const float v = sims[i];
  float e = expf(v);
  float p = (i < NDST) ? v : 0.f;
  e = wave_reduce(e);
  p = wave_reduce(p);
  __shared__ float se[4], sp[4];
  const int lane = threadIdx.x & 63, w = threadIdx.x >> 6;
  if (lane == 0) { se[w] = e; sp[w] = p; }
  __syncthreads();
  if (threadIdx.x == 0) {
    atomicAdd(red + 0, se[0] + se[1] + se[2] + se[3]);
    atomicAdd(red + 1, sp[0] + sp[1] + sp[2] + sp[3]);
  }
}

__global__ void k_final(const float* __restrict__ red, float* __restrict__ out) {
  out[0] = logf(red[0]) - red[1];
}

extern "C" void kernel_launch(void* const* d_in, const int* in_sizes, int n_in,
                              void* d_out, int out_size, void* d_ws, size_t ws_size,
                              hipStream_t stream) {
  const float* feat = (const float*)d_in[0];
  const int*   src  = (const int*)d_in[1];
  const int*   dst  = (const int*)d_in[2];
  const int*   nsrc = (const int*)d_in[3];
  const int*   ndst = (const int*)d_in[4];
  const float* W    = (const float*)d_in[5];
  const float* b    = (const float*)d_in[6];
  const float* pa   = (const float*)d_in[7];
  const int nE  = in_sizes[1];
  const int nEn = in_sizes[3];
  float* out = (float*)d_out;

  unsigned short* mb = (unsigned short*)d_ws;            // NTOT*256 bf16
  unsigned short* Wt = mb + (size_t)NTOT * 256;          // 256*256 bf16
  float* inn  = (float*)(Wt + 256 * 256);                // NSRC
  float* sims = inn + NSRC;                              // 3*NDST
  float* red  = sims + 3 * (size_t)NDST;                 // 8
  int* degP  = (int*)(red + 8);                          // NDST
  int* curP  = degP + NDST;                              // NDST
  int* degN  = curP + NDST;                              // NDST
  int* rsP   = degN + NDST;                              // NDST+1
  int* eSrcP = rsP + NDST + 1;                           // nE
  int* claim = eSrcP + nE;                               // nE ints

  hipMemsetAsync(degP, 0, 3 * (size_t)NDST * sizeof(int), stream);
  hipMemsetAsync(claim, 0, (size_t)nE * sizeof(int), stream);
  hipMemsetAsync(red, 0, 8 * sizeof(float), stream);

  const int nbP = (nE + 255) / 256, nbN = (nEn + 255) / 256;
  k_prep<<<256 + nbP + nbN, 256, 0, stream>>>(W, Wt, dst, ndst, degP, degN, nE, nEn);
  k_gemm_mfma<<<1024, 512, 0, stream>>>(feat, Wt, mb);
  k_scan<<<1, 256, 0, stream>>>(degP, rsP);
  k_fill<<<nbP, 256, 0, stream>>>(src, dst, rsP, curP, eSrcP, nE);
  k_claim_inn<<<nbN + NSRC / 4, 256, 0, stream>>>(nsrc, ndst, rsP, eSrcP, claim,
                                                  nEn, mb, b, pa, inn);
  k_fused<<<NDST / 4, 256, 0, stream>>>(mb, inn, rsP, eSrcP, claim, degN, b, pa,
                                        out + 1, sims);
  k_reduce<<<(3 * NDST) / 256, 256, 0, stream>>>(sims, red);
  k_final<<<1, 1, 0, stream>>>(red, out);
}

// Round 10
// 228.102 us; speedup vs baseline: 1.7501x; 1.0746x over previous
//
#include <hip/hip_runtime.h>
#include <math.h>

#define NSRC 32768
#define NTOT 65536
#define NDST 32768
#define DH   256

typedef __attribute__((ext_vector_type(8))) short bf16x8;
typedef __attribute__((ext_vector_type(4))) float f32x4;

__device__ __forceinline__ float wave_reduce(float v) {
#pragma unroll
  for (int off = 32; off > 0; off >>= 1) v += __shfl_xor(v, off, 64);
  return v;
}
__device__ __forceinline__ unsigned short f2bf(float f) {
  union { float f; unsigned u; } v; v.f = f;
  unsigned r = v.u + 0x7FFFu + ((v.u >> 16) & 1u);
  return (unsigned short)(r >> 16);
}
__device__ __forceinline__ float bf2f(unsigned short h) {
  union { unsigned u; float f; } v; v.u = ((unsigned)h) << 16;
  return v.f;
}
__device__ __forceinline__ float4 bf4(ushort4 v) {
  return make_float4(bf2f(v.x), bf2f(v.y), bf2f(v.z), bf2f(v.w));
}
__device__ __forceinline__ void add4(float4& a, const float4 v) {
  a.x += v.x; a.y += v.y; a.z += v.z; a.w += v.w;
}
__device__ __forceinline__ float4 sub4(const float4 a, const float4 v) {
  return make_float4(a.x - v.x, a.y - v.y, a.z - v.z, a.w - v.w);
}
__device__ __forceinline__ float dot4(const float4 a, const float4 b) {
  return a.x * b.x + a.y * b.y + a.z * b.z + a.w * b.w;
}
__device__ __forceinline__ float4 hsrc4(const float4 v, const float4 bv,
                                        float alpha, float isc) {
  float4 h;
  h.x = v.x + bv.x; h.x = (h.x >= 0.f ? h.x : alpha * h.x) * isc;
  h.y = v.y + bv.y; h.y = (h.y >= 0.f ? h.y : alpha * h.y) * isc;
  h.z = v.z + bv.z; h.z = (h.z >= 0.f ? h.z : alpha * h.z) * isc;
  h.w = v.w + bv.w; h.w = (h.w >= 0.f ? h.w : alpha * h.w) * isc;
  return h;
}

// ---------------- prep: cvtW + degP + degN (merged launches) ----------------
__global__ __launch_bounds__(256) void k_prep(const float* __restrict__ W,
                                              unsigned short* __restrict__ Wt,
                                              const int* __restrict__ dst,
                                              const int* __restrict__ ndst,
                                              int* __restrict__ degP,
                                              int* __restrict__ degN,
                                              int nE, int nEn) {
  int bid = blockIdx.x;
  const int t = threadIdx.x;
  if (bid < 256) {  // W transpose+cast
    Wt[bid * 256 + t] = f2bf(W[(size_t)t * 256 + bid]);
    return;
  }
  bid -= 256;
  const int nbP = (nE + 255) / 256;
  if (bid < nbP) {
    const int e = bid * 256 + t;
    if (e < nE) atomicAdd(&degP[dst[e] - NSRC], 1);
    return;
  }
  bid -= nbP;
  const int e = bid * 256 + t;
  if (e < nEn) atomicAdd(&degN[ndst[e] - NSRC], 1);
}

// ---------------- MFMA GEMM: feat read ONCE; 4 Wt-quarters thru 32KB LDS ----
// Grid 512 x 512thr (8 waves x 16 rows = 128 rows/block). Per quarter q:
// stage Wt cols [q*64,q*64+64) fragment-linear, 16 MFMAs/tile, store, reset.
// LDS slot (f=nt*8+ks, lane) holds lane's exact 16B A-fragment (conflict-free;
// mapping identical to the R8/R9-verified layout).
__global__ __launch_bounds__(512) void k_gemm_mfma(
    const float* __restrict__ A, const unsigned short* __restrict__ Wt,
    unsigned short* __restrict__ mb) {
  __shared__ unsigned short wl[16384];  // 32 KB
  const int bid = blockIdx.x;
  const int t = threadIdx.x;
  const int lane = t & 63;
  const int wv = t >> 6;             // 0..7
  const int ln = lane & 15;
  const int kq = lane >> 4;          // 0..3
  const int row = bid * 128 + wv * 16 + ln;

  // feat strip -> bf16 fragments (read once per row total)
  bf16x8 bs[8];
  const float* ap = A + (size_t)row * 256 + kq * 8;
#pragma unroll
  for (int ks = 0; ks < 8; ++ks) {
    float4 a0 = *(const float4*)(ap + ks * 32);
    float4 a1 = *(const float4*)(ap + ks * 32 + 4);
    bf16x8 v;
    v[0] = (short)f2bf(a0.x); v[1] = (short)f2bf(a0.y);
    v[2] = (short)f2bf(a0.z); v[3] = (short)f2bf(a0.w);
    v[4] = (short)f2bf(a1.x); v[5] = (short)f2bf(a1.y);
    v[6] = (short)f2bf(a1.z); v[7] = (short)f2bf(a1.w);
    bs[ks] = v;
  }

  for (int q = 0; q < 4; ++q) {
    __syncthreads();  // previous quarter's LDS reads retired before overwrite
#pragma unroll
    for (int r = 0; r < 4; ++r) {
      const int flat = r * 512 + t;   // 0..2047
      const int f = flat >> 6;        // nt*8 + ks, 0..31
      const int ls = flat & 63;
      const int n = q * 64 + (f >> 3) * 16 + (ls & 15);
      const int k = ((ls >> 4) << 3) + (f & 7) * 32;
      *(bf16x8*)(wl + flat * 8) = *(const bf16x8*)(Wt + (size_t)n * 256 + k);
    }
    __syncthreads();

    f32x4 acc[4];
#pragma unroll
    for (int i = 0; i < 4; ++i) acc[i] = (f32x4){0.f, 0.f, 0.f, 0.f};
#pragma unroll
    for (int nt = 0; nt < 4; ++nt) {
#pragma unroll
      for (int ks = 0; ks < 8; ++ks) {
        bf16x8 af = *(const bf16x8*)(wl + ((nt * 8 + ks) * 64 + lane) * 8);
        acc[nt] = __builtin_amdgcn_mfma_f32_16x16x32_bf16(af, bs[ks], acc[nt], 0, 0, 0);
      }
    }
    const int n0 = q * 64 + kq * 4;
#pragma unroll
    for (int nt = 0; nt < 4; ++nt) {
      ushort4 o;
      o.x = f2bf(acc[nt][0]); o.y = f2bf(acc[nt][1]);
      o.z = f2bf(acc[nt][2]); o.w = f2bf(acc[nt][3]);
      *(ushort4*)(mb + (size_t)row * 256 + n0 + nt * 16) = o;
    }
  }
}

// ---------------- scan (pos degrees -> rowStart), 1024 thr ------------------
__global__ __launch_bounds__(1024) void k_scan(const int* __restrict__ deg,
                                               int* __restrict__ rowStart) {
  __shared__ int tot[1024];
  const int t = threadIdx.x;
  const int base = t * 32;
  int s = 0;
  for (int i = 0; i < 32; ++i) s += deg[base + i];
  tot[t] = s;
  __syncthreads();
  for (int off = 1; off < 1024; off <<= 1) {
    int v = (t >= off) ? tot[t - off] : 0;
    __syncthreads();
    tot[t] += v;
    __syncthreads();
  }
  int pre = (t == 0) ? 0 : tot[t - 1];
  for (int i = 0; i < 32; ++i) {
    rowStart[base + i] = pre;
    pre += deg[base + i];
  }
  if (t == 1023) rowStart[NDST] = pre;
}

__global__ __launch_bounds__(256) void k_fill(const int* __restrict__ src,
                                              const int* __restrict__ dst,
                                              const int* __restrict__ rowStart,
                                              int* __restrict__ cur,
                                              int* __restrict__ eSrc, int nE) {
  const int e = blockIdx.x * 256 + threadIdx.x;
  if (e >= nE) return;
  const int d = dst[e] - NSRC;
  const int p = atomicAdd(&cur[d], 1);
  eSrc[rowStart[d] + p] = src[e];
}

// ---------------- claim (per NEG edge, CAS) + inn (merged) ------------------
__global__ __launch_bounds__(256) void k_claim_inn(
    const int* __restrict__ nsrc, const int* __restrict__ ndst,
    const int* __restrict__ rsP, const int* __restrict__ esP,
    int* __restrict__ claim, int nEn,
    const unsigned short* __restrict__ mb, const float* __restrict__ b,
    const float* __restrict__ pa, float* __restrict__ inn) {
  int bid = blockIdx.x;
  const int nbC = (nEn + 255) / 256;
  if (bid < nbC) {
    const int i = bid * 256 + threadIdx.x;
    if (i >= nEn) return;
    const int d = ndst[i] - NSRC;
    const int s = nsrc[i];
    const int p1 = rsP[d + 1];
    for (int j = rsP[d]; j < p1; ++j) {
      if (esP[j] == s) {
        if (atomicCAS(&claim[j], 0, 1) == 0) return;
      }
    }
    return;
  }
  bid -= nbC;
  const int row = bid * 4 + (threadIdx.x >> 6);
  const int lane = threadIdx.x & 63;
  const int c = lane * 4;
  float4 v = bf4(*(const ushort4*)(mb + (size_t)row * 256 + c));
  float4 bv = *(const float4*)(b + c);
  const float alpha = pa[0];
  float4 h = hsrc4(v, bv, alpha, 1.0f);
  float ss = wave_reduce(dot4(h, h));
  if (lane == 0) inn[row] = 1.0f / fmaxf(sqrtf(ss), 1e-8f);
}

// ---------------- fused: agg(P,N) + prelu + norm + all loss terms -----------
// Complement accumulation (aN=aP-aU); 8/4/1 unroll cascade for gather MLP.
// No __syncthreads / global atomics here (round-7 regression lesson).
__global__ __launch_bounds__(256) void k_fused(const unsigned short* __restrict__ mb,
                                               const float* __restrict__ inn,
                                               const int* __restrict__ rsP,
                                               const int* __restrict__ esP,
                                               const int* __restrict__ claim,
                                               const int* __restrict__ degN,
                                               const float* __restrict__ b,
                                               const float* __restrict__ pa,
                                               float* __restrict__ hraw,
                                               float* __restrict__ sims) {
  const int row = blockIdx.x * 4 + (threadIdx.x >> 6);
  const int lane = threadIdx.x & 63;
  const int c = lane * 4;
  const int p0 = rsP[row], p1 = rsP[row + 1];
  const int cN = degN[row];
  const float4 bv = *(const float4*)(b + c);
  const float alpha = pa[0];

  float4 self = bf4(*(const ushort4*)(mb + (size_t)(NSRC + row) * 256 + c));
  float4 aP0 = self, aP1 = {0.f, 0.f, 0.f, 0.f};
  float4 sP0 = {0.f, 0.f, 0.f, 0.f}, sP1 = {0.f, 0.f, 0.f, 0.f};
  float4 aU0 = {0.f, 0.f, 0.f, 0.f}, aU1 = {0.f, 0.f, 0.f, 0.f};
  float4 sU0 = {0.f, 0.f, 0.f, 0.f}, sU1 = {0.f, 0.f, 0.f, 0.f};

  int e = p0;
  for (; e + 7 < p1; e += 8) {
    int sx[8]; ushort4 rx[8];
#pragma unroll
    for (int u = 0; u < 8; ++u) sx[u] = esP[e + u];
#pragma unroll
    for (int u = 0; u < 8; ++u)
      rx[u] = *(const ushort4*)(mb + (size_t)sx[u] * 256 + c);
    int clx[8]; float ix[8];
#pragma unroll
    for (int u = 0; u < 8; ++u) { clx[u] = claim[e + u]; ix[u] = inn[sx[u]]; }
#pragma unroll
    for (int u = 0; u < 8; ++u) {
      float4 v = bf4(rx[u]);
      float4 h = hsrc4(v, bv, alpha, ix[u]);
      if (u & 1) { add4(aP1, v); add4(sP1, h); } else { add4(aP0, v); add4(sP0, h); }
      if (!clx[u]) {
        if (u & 1) { add4(aU1, v); add4(sU1, h); } else { add4(aU0, v); add4(sU0, h); }
      }
    }
  }
  for (; e + 3 < p1; e += 4) {
    const int s0 = esP[e], s1 = esP[e + 1], s2 = esP[e + 2], s3 = esP[e + 3];
    ushort4 r0 = *(const ushort4*)(mb + (size_t)s0 * 256 + c);
    ushort4 r1 = *(const ushort4*)(mb + (size_t)s1 * 256 + c);
    ushort4 r2 = *(const ushort4*)(mb + (size_t)s2 * 256 + c);
    ushort4 r3 = *(const ushort4*)(mb + (size_t)s3 * 256 + c);
    const int cl0 = claim[e], cl1 = claim[e + 1], cl2 = claim[e + 2], cl3 = claim[e + 3];
    const float i0 = inn[s0], i1 = inn[s1], i2 = inn[s2], i3 = inn[s3];
    float4 v0 = bf4(r0), v1 = bf4(r1), v2 = bf4(r2), v3 = bf4(r3);
    float4 h0 = hsrc4(v0, bv, alpha, i0);
    float4 h1 = hsrc4(v1, bv, alpha, i1);
    float4 h2 = hsrc4(v2, bv, alpha, i2);
    float4 h3 = hsrc4(v3, bv, alpha, i3);
    add4(aP0, v0); add4(aP1, v1); add4(aP0, v2); add4(aP1, v3);
    add4(sP0, h0); add4(sP1, h1); add4(sP0, h2); add4(sP1, h3);
    if (!cl0) { add4(aU0, v0); add4(sU0, h0); }
    if (!cl1) { add4(aU1, v1); add4(sU1, h1); }
    if (!cl2) { add4(aU0, v2); add4(sU0, h2); }
    if (!cl3) { add4(aU1, v3); add4(sU1, h3); }
  }
  for (; e < p1; ++e) {
    const int s0 = esP[e];
    const int cl0 = claim[e];
    const float i0 = inn[s0];
    float4 v0 = bf4(*(const ushort4*)(mb + (size_t)s0 * 256 + c));
    float4 h0 = hsrc4(v0, bv, alpha, i0);
    add4(aP0, v0); add4(sP0, h0);
    if (!cl0) { add4(aU0, v0); add4(sU0, h0); }
  }
  add4(aP0, aP1); add4(sP0, sP1); add4(aU0, aU1); add4(sU0, sU1);
  float4 aN0 = sub4(aP0, aU0);
  float4 sN0 = sub4(sP0, sU0);

  const float invP = 1.0f / (float)(p1 - p0 + 1);
  const float invN = 1.0f / (float)(cN + 1);
  float4 hp, hn;
  hp.x = aP0.x * invP + bv.x; hp.x = hp.x >= 0.f ? hp.x : alpha * hp.x;
  hp.y = aP0.y * invP + bv.y; hp.y = hp.y >= 0.f ? hp.y : alpha * hp.y;
  hp.z = aP0.z * invP + bv.z; hp.z = hp.z >= 0.f ? hp.z : alpha * hp.z;
  hp.w = aP0.w * invP + bv.w; hp.w = hp.w >= 0.f ? hp.w : alpha * hp.w;
  hn.x = aN0.x * invN + bv.x; hn.x = hn.x >= 0.f ? hn.x : alpha * hn.x;
  hn.y = aN0.y * invN + bv.y; hn.y = hn.y >= 0.f ? hn.y : alpha * hn.y;
  hn.z = aN0.z * invN + bv.z; hn.z = hn.z >= 0.f ? hn.z : alpha * hn.z;
  hn.w = aN0.w * invN + bv.w; hn.w = hn.w >= 0.f ? hn.w : alpha * hn.w;

  *(float4*)(hraw + (size_t)row * 256 + c) = hp;  // h_pos[NSRC:] output

  float ssP = wave_reduce(dot4(hp, hp));
  float ssN = wave_reduce(dot4(hn, hn));
  const float iP = 1.0f / fmaxf(sqrtf(ssP), 1e-8f);
  const float iN = 1.0f / fmaxf(sqrtf(ssN), 1e-8f);
  float4 xp = hp, xn = hn;
  xp.x *= iP; xp.y *= iP; xp.z *= iP; xp.w *= iP;
  xn.x *= iN; xn.y *= iN; xn.z *= iN; xn.w *= iN;

  float pos = wave_reduce(dot4(xp, xn));
  float n1 = wave_reduce(dot4(xp, sN0));
  float n2 = wave_reduce(dot4(xn, sP0));
  if (lane == 0) {
    sims[row] = pos;
    sims[NDST + row] = pos + n1;       // + self-loop term
    sims[2 * NDST + row] = pos + n2;   // + self-loop term
  }
}

// ---------------- final log-sum-exp reduce ----------------------------------
__global__ __launch_bounds__(256) void k_reduce(const float* __restrict__ sims,
                                                float* __restrict__ red) {
  const int i = blockIdx.x * 256 + threadIdx.x;
  const float v = sims[i];
  float e = expf(v);
  float p = (i < NDST) ? v : 0.f;
  e = wave_reduce(e);
  p = wave_reduce(p);
  __shared__ float se[4], sp[4];
  const int lane = threadIdx.x & 63, w = threadIdx.x >> 6;
  if (lane == 0) { se[w] = e; sp[w] = p; }
  __syncthreads();
  if (threadIdx.x == 0) {
    atomicAdd(red + 0, se[0] + se[1] + se[2] + se[3]);
    atomicAdd(red + 1, sp[0] + sp[1] + sp[2] + sp[3]);
  }
}

__global__ void k_final(const float* __restrict__ red, float* __restrict__ out) {
  out[0] = logf(red[0]) - red[1];
}

extern "C" void kernel_launch(void* const* d_in, const int* in_sizes, int n_in,
                              void* d_out, int out_size, void* d_ws, size_t ws_size,
                              hipStream_t stream) {
  const float* feat = (const float*)d_in[0];
  const int*   src  = (const int*)d_in[1];
  const int*   dst  = (const int*)d_in[2];
  const int*   nsrc = (const int*)d_in[3];
  const int*   ndst = (const int*)d_in[4];
  const float* W    = (const float*)d_in[5];
  const float* b    = (const float*)d_in[6];
  const float* pa   = (const float*)d_in[7];
  const int nE  = in_sizes[1];
  const int nEn = in_sizes[3];
  float* out = (float*)d_out;

  unsigned short* mb = (unsigned short*)d_ws;            // NTOT*256 bf16
  unsigned short* Wt = mb + (size_t)NTOT * 256;          // 256*256 bf16
  float* inn  = (float*)(Wt + 256 * 256);                // NSRC
  float* sims = inn + NSRC;                              // 3*NDST
  float* red  = sims + 3 * (size_t)NDST;                 // 8
  int* degP  = (int*)(red + 8);                          // NDST
  int* curP  = degP + NDST;                              // NDST
  int* degN  = curP + NDST;                              // NDST
  int* rsP   = degN + NDST;                              // NDST+1
  int* eSrcP = rsP + NDST + 1;                           // nE
  int* claim = eSrcP + nE;                               // nE ints

  hipMemsetAsync(degP, 0, 3 * (size_t)NDST * sizeof(int), stream);
  hipMemsetAsync(claim, 0, (size_t)nE * sizeof(int), stream);
  hipMemsetAsync(red, 0, 8 * sizeof(float), stream);

  const int nbP = (nE + 255) / 256, nbN = (nEn + 255) / 256;
  k_prep<<<256 + nbP + nbN, 256, 0, stream>>>(W, Wt, dst, ndst, degP, degN, nE, nEn);
  k_gemm_mfma<<<512, 512, 0, stream>>>(feat, Wt, mb);
  k_scan<<<1, 1024, 0, stream>>>(degP, rsP);
  k_fill<<<nbP, 256, 0, stream>>>(src, dst, rsP, curP, eSrcP, nE);
  k_claim_inn<<<nbN + NSRC / 4, 256, 0, stream>>>(nsrc, ndst, rsP, eSrcP, claim,
                                                  nEn, mb, b, pa, inn);
  k_fused<<<NDST / 4, 256, 0, stream>>>(mb, inn, rsP, eSrcP, claim, degN, b, pa,
                                        out + 1, sims);
  k_reduce<<<(3 * NDST) / 256, 256, 0, stream>>>(sims, red);
  k_final<<<1, 1, 0, stream>>>(red, out);
}

// Round 11
// 188.430 us; speedup vs baseline: 2.1185x; 1.2105x over previous
//
#include <hip/hip_runtime.h>
#include <math.h>

#define NSRC 32768
#define NTOT 65536
#define NDST 32768
#define DH   256
#define SLOTS 64

typedef __attribute__((ext_vector_type(8))) short bf16x8;
typedef __attribute__((ext_vector_type(4))) float f32x4;

__device__ __forceinline__ float wave_reduce(float v) {
#pragma unroll
  for (int off = 32; off > 0; off >>= 1) v += __shfl_xor(v, off, 64);
  return v;
}
__device__ __forceinline__ unsigned short f2bf(float f) {
  union { float f; unsigned u; } v; v.f = f;
  unsigned r = v.u + 0x7FFFu + ((v.u >> 16) & 1u);
  return (unsigned short)(r >> 16);
}
__device__ __forceinline__ float bf2f(unsigned short h) {
  union { unsigned u; float f; } v; v.u = ((unsigned)h) << 16;
  return v.f;
}
__device__ __forceinline__ float4 bf4(ushort4 v) {
  return make_float4(bf2f(v.x), bf2f(v.y), bf2f(v.z), bf2f(v.w));
}
__device__ __forceinline__ void add4(float4& a, const float4 v) {
  a.x += v.x; a.y += v.y; a.z += v.z; a.w += v.w;
}
__device__ __forceinline__ float4 sub4(const float4 a, const float4 v) {
  return make_float4(a.x - v.x, a.y - v.y, a.z - v.z, a.w - v.w);
}
__device__ __forceinline__ float dot4(const float4 a, const float4 b) {
  return a.x * b.x + a.y * b.y + a.z * b.z + a.w * b.w;
}
__device__ __forceinline__ float4 hsrc4(const float4 v, const float4 bv,
                                        float alpha, float isc) {
  float4 h;
  h.x = v.x + bv.x; h.x = (h.x >= 0.f ? h.x : alpha * h.x) * isc;
  h.y = v.y + bv.y; h.y = (h.y >= 0.f ? h.y : alpha * h.y) * isc;
  h.z = v.z + bv.z; h.z = (h.z >= 0.f ? h.z : alpha * h.z) * isc;
  h.w = v.w + bv.w; h.w = (h.w >= 0.f ? h.w : alpha * h.w) * isc;
  return h;
}

// ---------------- prep: cvtW + fixed-slot fill(P) + degN (one launch) -------
__global__ __launch_bounds__(256) void k_prep(const float* __restrict__ W,
                                              unsigned short* __restrict__ Wt,
                                              const int* __restrict__ src,
                                              const int* __restrict__ dst,
                                              const int* __restrict__ ndst,
                                              int* __restrict__ cur,
                                              int* __restrict__ eSrc,
                                              int* __restrict__ degN,
                                              int nE, int nEn) {
  int bid = blockIdx.x;
  const int t = threadIdx.x;
  if (bid < 256) {  // W transpose+cast
    Wt[bid * 256 + t] = f2bf(W[(size_t)t * 256 + bid]);
    return;
  }
  bid -= 256;
  const int nbP = (nE + 255) / 256;
  if (bid < nbP) {  // pos fill: fixed-slot CSR (64 slots/row; P(deg>64)~1e-20)
    const int e = bid * 256 + t;
    if (e < nE) {
      const int d = dst[e] - NSRC;
      const int p = atomicAdd(&cur[d], 1);
      if (p < SLOTS) eSrc[d * SLOTS + p] = src[e];
    }
    return;
  }
  bid -= nbP;
  const int e = bid * 256 + t;
  if (e < nEn) atomicAdd(&degN[ndst[e] - NSRC], 1);
}

// ---------------- MFMA GEMM + fused inn epilogue for src rows ---------------
// Grid 512 x 512thr; 128 rows/block; feat read once; 4 Wt-quarters via 32KB
// LDS, fragment-linear (verified layout). Blocks 0..255 (= rows < NSRC) also
// accumulate ss = |prelu(m+b)|^2 in f32 and emit inn[row].
__global__ __launch_bounds__(512) void k_gemm_mfma(
    const float* __restrict__ A, const unsigned short* __restrict__ Wt,
    const float* __restrict__ b, const float* __restrict__ pa,
    unsigned short* __restrict__ mb, float* __restrict__ inn) {
  __shared__ unsigned short wl[16384];  // 32 KB
  const int bid = blockIdx.x;
  const int t = threadIdx.x;
  const int lane = t & 63;
  const int wv = t >> 6;             // 0..7
  const int ln = lane & 15;
  const int kq = lane >> 4;          // 0..3
  const int row = bid * 128 + wv * 16 + ln;
  const bool is_src = (bid < 256);
  const float alpha = pa[0];

  bf16x8 bs[8];
  const float* ap = A + (size_t)row * 256 + kq * 8;
#pragma unroll
  for (int ks = 0; ks < 8; ++ks) {
    float4 a0 = *(const float4*)(ap + ks * 32);
    float4 a1 = *(const float4*)(ap + ks * 32 + 4);
    bf16x8 v;
    v[0] = (short)f2bf(a0.x); v[1] = (short)f2bf(a0.y);
    v[2] = (short)f2bf(a0.z); v[3] = (short)f2bf(a0.w);
    v[4] = (short)f2bf(a1.x); v[5] = (short)f2bf(a1.y);
    v[6] = (short)f2bf(a1.z); v[7] = (short)f2bf(a1.w);
    bs[ks] = v;
  }

  float ss = 0.f;
  for (int q = 0; q < 4; ++q) {
    __syncthreads();
#pragma unroll
    for (int r = 0; r < 4; ++r) {
      const int flat = r * 512 + t;   // 0..2047
      const int f = flat >> 6;        // nt*8 + ks
      const int ls = flat & 63;
      const int n = q * 64 + (f >> 3) * 16 + (ls & 15);
      const int k = ((ls >> 4) << 3) + (f & 7) * 32;
      *(bf16x8*)(wl + flat * 8) = *(const bf16x8*)(Wt + (size_t)n * 256 + k);
    }
    __syncthreads();

    f32x4 acc[4];
#pragma unroll
    for (int i = 0; i < 4; ++i) acc[i] = (f32x4){0.f, 0.f, 0.f, 0.f};
#pragma unroll
    for (int nt = 0; nt < 4; ++nt) {
#pragma unroll
      for (int ks = 0; ks < 8; ++ks) {
        bf16x8 af = *(const bf16x8*)(wl + ((nt * 8 + ks) * 64 + lane) * 8);
        acc[nt] = __builtin_amdgcn_mfma_f32_16x16x32_bf16(af, bs[ks], acc[nt], 0, 0, 0);
      }
    }
    const int n0 = q * 64 + kq * 4;
#pragma unroll
    for (int nt = 0; nt < 4; ++nt) {
      ushort4 o;
      o.x = f2bf(acc[nt][0]); o.y = f2bf(acc[nt][1]);
      o.z = f2bf(acc[nt][2]); o.w = f2bf(acc[nt][3]);
      *(ushort4*)(mb + (size_t)row * 256 + n0 + nt * 16) = o;
      if (is_src) {
        float4 bv = *(const float4*)(b + n0 + nt * 16);
        float hx = acc[nt][0] + bv.x; hx = hx >= 0.f ? hx : alpha * hx;
        float hy = acc[nt][1] + bv.y; hy = hy >= 0.f ? hy : alpha * hy;
        float hz = acc[nt][2] + bv.z; hz = hz >= 0.f ? hz : alpha * hz;
        float hw = acc[nt][3] + bv.w; hw = hw >= 0.f ? hw : alpha * hw;
        ss += hx * hx + hy * hy + hz * hz + hw * hw;
      }
    }
  }
  if (is_src) {
    ss += __shfl_xor(ss, 16, 64);
    ss += __shfl_xor(ss, 32, 64);
    if (kq == 0) inn[row] = 1.0f / fmaxf(sqrtf(ss), 1e-8f);
  }
}

// ---------------- parallel claim: one thread per NEG edge, CAS matching -----
__global__ __launch_bounds__(256) void k_claim(const int* __restrict__ nsrc,
                                               const int* __restrict__ ndst,
                                               const int* __restrict__ cur,
                                               const int* __restrict__ eSrc,
                                               int* __restrict__ claim, int nEn) {
  const int i = blockIdx.x * 256 + threadIdx.x;
  if (i >= nEn) return;
  const int d = ndst[i] - NSRC;
  const int s = nsrc[i];
  const int cnt = cur[d];
  const int base = d * SLOTS;
  for (int j = 0; j < cnt; ++j) {
    if (eSrc[base + j] == s) {
      if (atomicCAS(&claim[base + j], 0, 1) == 0) return;
    }
  }
}

// ---------------- fused: agg(P,N) + prelu + norm + all loss terms -----------
// Complement accumulation (aN=aP-aU); 4/1 unroll (R10: 8-wide hurt occupancy).
// No __syncthreads / global atomics here (R7 regression lesson).
__global__ __launch_bounds__(256) void k_fused(const unsigned short* __restrict__ mb,
                                               const float* __restrict__ inn,
                                               const int* __restrict__ cur,
                                               const int* __restrict__ eSrc,
                                               const int* __restrict__ claim,
                                               const int* __restrict__ degN,
                                               const float* __restrict__ b,
                                               const float* __restrict__ pa,
                                               float* __restrict__ hraw,
                                               float* __restrict__ sims) {
  const int row = blockIdx.x * 4 + (threadIdx.x >> 6);
  const int lane = threadIdx.x & 63;
  const int c = lane * 4;
  const int cnt = cur[row];
  const int base = row * SLOTS;
  const int cN = degN[row];
  const float4 bv = *(const float4*)(b + c);
  const float alpha = pa[0];

  float4 self = bf4(*(const ushort4*)(mb + (size_t)(NSRC + row) * 256 + c));
  float4 aP0 = self, aP1 = {0.f, 0.f, 0.f, 0.f};
  float4 sP0 = {0.f, 0.f, 0.f, 0.f}, sP1 = {0.f, 0.f, 0.f, 0.f};
  float4 aU0 = {0.f, 0.f, 0.f, 0.f}, aU1 = {0.f, 0.f, 0.f, 0.f};
  float4 sU0 = {0.f, 0.f, 0.f, 0.f}, sU1 = {0.f, 0.f, 0.f, 0.f};

  int e = 0;
  for (; e + 3 < cnt; e += 4) {
    const int s0 = eSrc[base + e],     s1 = eSrc[base + e + 1];
    const int s2 = eSrc[base + e + 2], s3 = eSrc[base + e + 3];
    ushort4 r0 = *(const ushort4*)(mb + (size_t)s0 * 256 + c);
    ushort4 r1 = *(const ushort4*)(mb + (size_t)s1 * 256 + c);
    ushort4 r2 = *(const ushort4*)(mb + (size_t)s2 * 256 + c);
    ushort4 r3 = *(const ushort4*)(mb + (size_t)s3 * 256 + c);
    const int cl0 = claim[base + e],     cl1 = claim[base + e + 1];
    const int cl2 = claim[base + e + 2], cl3 = claim[base + e + 3];
    const float i0 = inn[s0], i1 = inn[s1], i2 = inn[s2], i3 = inn[s3];
    float4 v0 = bf4(r0), v1 = bf4(r1), v2 = bf4(r2), v3 = bf4(r3);
    float4 h0 = hsrc4(v0, bv, alpha, i0);
    float4 h1 = hsrc4(v1, bv, alpha, i1);
    float4 h2 = hsrc4(v2, bv, alpha, i2);
    float4 h3 = hsrc4(v3, bv, alpha, i3);
    add4(aP0, v0); add4(aP1, v1); add4(aP0, v2); add4(aP1, v3);
    add4(sP0, h0); add4(sP1, h1); add4(sP0, h2); add4(sP1, h3);
    if (!cl0) { add4(aU0, v0); add4(sU0, h0); }
    if (!cl1) { add4(aU1, v1); add4(sU1, h1); }
    if (!cl2) { add4(aU0, v2); add4(sU0, h2); }
    if (!cl3) { add4(aU1, v3); add4(sU1, h3); }
  }
  for (; e < cnt; ++e) {
    const int s0 = eSrc[base + e];
    const int cl0 = claim[base + e];
    const float i0 = inn[s0];
    float4 v0 = bf4(*(const ushort4*)(mb + (size_t)s0 * 256 + c));
    float4 h0 = hsrc4(v0, bv, alpha, i0);
    add4(aP0, v0); add4(sP0, h0);
    if (!cl0) { add4(aU0, v0); add4(sU0, h0); }
  }
  add4(aP0, aP1); add4(sP0, sP1); add4(aU0, aU1); add4(sU0, sU1);
  float4 aN0 = sub4(aP0, aU0);
  float4 sN0 = sub4(sP0, sU0);

  const float invP = 1.0f / (float)(cnt + 1);
  const float invN = 1.0f / (float)(cN + 1);
  float4 hp, hn;
  hp.x = aP0.x * invP + bv.x; hp.x = hp.x >= 0.f ? hp.x : alpha * hp.x;
  hp.y = aP0.y * invP + bv.y; hp.y = hp.y >= 0.f ? hp.y : alpha * hp.y;
  hp.z = aP0.z * invP + bv.z; hp.z = hp.z >= 0.f ? hp.z : alpha * hp.z;
  hp.w = aP0.w * invP + bv.w; hp.w = hp.w >= 0.f ? hp.w : alpha * hp.w;
  hn.x = aN0.x * invN + bv.x; hn.x = hn.x >= 0.f ? hn.x : alpha * hn.x;
  hn.y = aN0.y * invN + bv.y; hn.y = hn.y >= 0.f ? hn.y : alpha * hn.y;
  hn.z = aN0.z * invN + bv.z; hn.z = hn.z >= 0.f ? hn.z : alpha * hn.z;
  hn.w = aN0.w * invN + bv.w; hn.w = hn.w >= 0.f ? hn.w : alpha * hn.w;

  *(float4*)(hraw + (size_t)row * 256 + c) = hp;  // h_pos[NSRC:] output

  float ssP = wave_reduce(dot4(hp, hp));
  float ssN = wave_reduce(dot4(hn, hn));
  const float iP = 1.0f / fmaxf(sqrtf(ssP), 1e-8f);
  const float iN = 1.0f / fmaxf(sqrtf(ssN), 1e-8f);
  float4 xp = hp, xn = hn;
  xp.x *= iP; xp.y *= iP; xp.z *= iP; xp.w *= iP;
  xn.x *= iN; xn.y *= iN; xn.z *= iN; xn.w *= iN;

  float pos = wave_reduce(dot4(xp, xn));
  float n1 = wave_reduce(dot4(xp, sN0));
  float n2 = wave_reduce(dot4(xn, sP0));
  if (lane == 0) {
    sims[row] = pos;
    sims[NDST + row] = pos + n1;       // + self-loop term
    sims[2 * NDST + row] = pos + n2;   // + self-loop term
  }
}

// ---------------- final log-sum-exp reduce ----------------------------------
__global__ __launch_bounds__(256) void k_reduce(const float* __restrict__ sims,
                                                float* __restrict__ red) {
  const int i = blockIdx.x * 256 + threadIdx.x;
  const float v = sims[i];
  float e = expf(v);
  float p = (i < NDST) ? v : 0.f;
  e = wave_reduce(e);
  p = wave_reduce(p);
  __shared__ float se[4], sp[4];
  const int lane = threadIdx.x & 63, w = threadIdx.x >> 6;
  if (lane == 0) { se[w] = e; sp[w] = p; }
  __syncthreads();
  if (threadIdx.x == 0) {
    atomicAdd(red + 0, se[0] + se[1] + se[2] + se[3]);
    atomicAdd(red + 1, sp[0] + sp[1] + sp[2] + sp[3]);
  }
}

__global__ void k_final(const float* __restrict__ red, float* __restrict__ out) {
  out[0] = logf(red[0]) - red[1];
}

extern "C" void kernel_launch(void* const* d_in, const int* in_sizes, int n_in,
                              void* d_out, int out_size, void* d_ws, size_t ws_size,
                              hipStream_t stream) {
  const float* feat = (const float*)d_in[0];
  const int*   src  = (const int*)d_in[1];
  const int*   dst  = (const int*)d_in[2];
  const int*   nsrc = (const int*)d_in[3];
  const int*   ndst = (const int*)d_in[4];
  const float* W    = (const float*)d_in[5];
  const float* b    = (const float*)d_in[6];
  const float* pa   = (const float*)d_in[7];
  const int nE  = in_sizes[1];
  const int nEn = in_sizes[3];
  float* out = (float*)d_out;

  unsigned short* mb = (unsigned short*)d_ws;            // NTOT*256 bf16
  unsigned short* Wt = mb + (size_t)NTOT * 256;          // 256*256 bf16
  float* inn  = (float*)(Wt + 256 * 256);                // NSRC
  float* sims = inn + NSRC;                              // 3*NDST
  int* eSrc = (int*)(sims + 3 * (size_t)NDST);           // NDST*SLOTS
  // ---- contiguous zero-region: cur | degN | red | claim (one memset) ----
  int* cur  = eSrc + (size_t)NDST * SLOTS;               // NDST
  int* degN = cur + NDST;                                // NDST
  float* red = (float*)(degN + NDST);                    // 8
  int* claim = (int*)(red + 8);                          // NDST*SLOTS
  const size_t zero_bytes = (2 * (size_t)NDST + 8 + (size_t)NDST * SLOTS) * 4;

  hipMemsetAsync(cur, 0, zero_bytes, stream);

  const int nbP = (nE + 255) / 256, nbN = (nEn + 255) / 256;
  k_prep<<<256 + nbP + nbN, 256, 0, stream>>>(W, Wt, src, dst, ndst, cur, eSrc,
                                              degN, nE, nEn);
  k_gemm_mfma<<<512, 512, 0, stream>>>(feat, Wt, b, pa, mb, inn);
  k_claim<<<nbN, 256, 0, stream>>>(nsrc, ndst, cur, eSrc, claim, nEn);
  k_fused<<<NDST / 4, 256, 0, stream>>>(mb, inn, cur, eSrc, claim, degN, b, pa,
                                        out + 1, sims);
  k_reduce<<<(3 * NDST) / 256, 256, 0, stream>>>(sims, red);
  k_final<<<1, 1, 0, stream>>>(red, out);
}